// Round 6
// baseline (144.669 us; speedup 1.0000x reference)
//
#include <hip/hip_runtime.h>
#include <hip/hip_bf16.h>

typedef _Float16 f16;
typedef _Float16 f16x2 __attribute__((ext_vector_type(2)));
typedef _Float16 f16x4 __attribute__((ext_vector_type(4)));
typedef _Float16 f16x8 __attribute__((ext_vector_type(8)));
typedef float f32x4 __attribute__((ext_vector_type(4)));
typedef float f32x16 __attribute__((ext_vector_type(16)));

#define T_TOK 4096
#define V_N 32
#define H_N 256
#define LN_EPS_F 1e-5f

union U4 { f16x4 h; int i[2]; };
union U8 { f16x8 h; int i[4]; };

__device__ __forceinline__ void gload16(const f16* g, f16* l) {
    __builtin_amdgcn_global_load_lds(
        (const __attribute__((address_space(1))) void*)g,
        (__attribute__((address_space(3))) void*)l, 16, 0, 0);
}

// ---------------- prep: W2,Wg [v][k][n] f32 -> [v][n][k] f16 ----------------
__global__ __launch_bounds__(256) void prep_transpose(
    const float* __restrict__ W2, const float* __restrict__ Wg,
    f16* __restrict__ W2t, f16* __restrict__ Wgt)
{
    __shared__ float tile[64][65];
    int bid = blockIdx.x;
    int w = bid >> 9;
    int rem = bid & 511;
    int v = rem >> 4;
    int kt = (rem >> 2) & 3;
    int nt = rem & 3;
    const float* src = w ? Wg : W2;
    f16* dst = w ? Wgt : W2t;
    const float* base = src + ((size_t)v * H_N + (size_t)kt * 64) * H_N + nt * 64;
    int tid = threadIdx.x;
    #pragma unroll
    for (int p = 0; p < 16; ++p) {
        int idx = p * 256 + tid;
        int r = idx >> 6, c = idx & 63;
        tile[r][c] = base[(size_t)r * H_N + c];
    }
    __syncthreads();
    f16* obase = dst + ((size_t)v * H_N + (size_t)nt * 64) * H_N + kt * 64;
    #pragma unroll
    for (int p = 0; p < 16; ++p) {
        int idx = p * 256 + tid;
        int r = idx >> 6, c = idx & 63;
        obase[(size_t)r * H_N + c] = (f16)tile[c][r];
    }
}

// ---------------- prep: W1,b1 f32 -> f16 ----------------
__global__ __launch_bounds__(256) void prep_w1(
    const float* __restrict__ W1, const float* __restrict__ b1,
    f16* __restrict__ W1h, f16* __restrict__ b1h)
{
    int i = blockIdx.x * 256 + threadIdx.x;   // grid 32 -> 8192
    W1h[i] = (f16)W1[i];
    b1h[i] = (f16)b1[i];
}

// ---------------- fused GRN: swapped-operand, 32x32x16 MFMA, LDS-staged weights ----
// grid 1024 = (v, mt32), 256 thr = 4 waves; each lane owns ONE token (32/wave).
// Weight 32k-slices double-buffered in LDS via global_load_lds; chunk-XOR swizzle
// c_stored = c ^ (n&3) gives uniform 8-words/bank on both write and read.
// MFMA 32x32x16: A row = lane&31, k = (lane>>5)*8+e; B col = lane&31, same k;
// C/D col = lane&31, row = (reg&3) + 8*(reg>>2) + 4*(lane>>5)  [guide-verified].
__global__ __launch_bounds__(256, 2) void fused_grn(
    const float* __restrict__ x,    // [T][V]
    const f16* __restrict__ W1h, const f16* __restrict__ b1h,   // [V][256]
    const f16* __restrict__ W2t, const float* __restrict__ b2,  // [V][n][k]
    const f16* __restrict__ Wgt, const float* __restrict__ bg,
    const float* __restrict__ gamma, const float* __restrict__ beta,
    const float* __restrict__ Wa, const float* __restrict__ ba,
    f16* __restrict__ VO,           // [V][T][H]
    float* __restrict__ scores)     // [T][V]
{
    __shared__ f16 Wb[2][256 * 32];  // two 16KB k-slices (256 n x 32 k)

    int bid = blockIdx.x;
    int xcd = bid & 7, rr = bid >> 3;
    int v  = (xcd << 2) + (rr >> 5);   // 4 variables per XCD -> weights L2-local
    int mt = rr & 31;
    int tid = threadIdx.x;
    int w = tid >> 6, lane = tid & 63;
    int col = lane & 31, h = lane >> 5;
    int m = mt * 128 + w * 32 + col;   // this lane's token row

    const f16* W2v = W2t + ((size_t)v << 16);
    const f16* Wgv = Wgt + ((size_t)v << 16);

    // stage 32k-slice s into Wb[buf]; linear LDS dest, source chunk pre-swizzled
    auto stage = [&](const f16* Wv, int s, int buf) {
        int cs = (lane & 3) ^ ((lane >> 2) & 3);
        #pragma unroll
        for (int i = 0; i < 4; ++i) {
            int n = ((w * 4 + i) << 4) + (lane >> 2);
            gload16(Wv + ((size_t)n << 8) + (s << 5) + (cs << 3),
                    &Wb[buf][(w * 4 + i) << 9]);
        }
    };

    float xs = x[(size_t)m * V_N + v];
    f16 xh = (f16)xs;
    f16x8 x8 = { xh, xh, xh, xh, xh, xh, xh, xh };

    f32x16 acc[8] = {};
    const int rowoff = col << 5;       // f16 offset of row (col) within an nb block
    const int cxor = col & 3;          // chunk swizzle term

    stage(W2v, 0, 0);
    __syncthreads();

    // ---- GEMM1: H2 = relu(x*W1+b1) @ W2 ; B-frag (h1^T) generated in-register ----
    #pragma unroll
    for (int s = 0; s < 8; ++s) {
        if (s < 7) stage(W2v, s + 1, (s + 1) & 1);
        else       stage(Wgv, 0, 0);          // prefetch GEMM2 slice 0
        #pragma unroll
        for (int t = 0; t < 2; ++t) {
            const int kt = 2 * s + t;
            const int k0 = (kt << 4) + (h << 3);
            f16x8 w8 = *(const f16x8*)&W1h[(v << 8) + k0];
            f16x8 c8 = *(const f16x8*)&b1h[(v << 8) + k0];
            f16x8 hv = x8 * w8 + c8;
            #pragma unroll
            for (int j = 0; j < 8; ++j) hv[j] = hv[j] > (f16)0 ? hv[j] : (f16)0;
            const int chunk = ((t << 1) + h) ^ cxor;
            #pragma unroll
            for (int nb = 0; nb < 8; ++nb) {
                f16x8 af = *(const f16x8*)&Wb[s & 1][(nb << 10) + rowoff + (chunk << 3)];
                acc[nb] = __builtin_amdgcn_mfma_f32_32x32x16_f16(af, hv, acc[nb], 0, 0, 0);
            }
        }
        __syncthreads();
    }

    // ---- H2 += b2, pack to f16 ints (registers); re-zero acc ----
    int H2i[64];   // [nb][2p + {0,1}]: int nb*8+2p = regs 4p,4p+1 (f16 pair)
    #pragma unroll
    for (int nb = 0; nb < 8; ++nb) {
        #pragma unroll
        for (int p = 0; p < 4; ++p) {
            int n0 = (nb << 5) + (p << 3) + (h << 2);
            f32x4 b4 = *(const f32x4*)&b2[(v << 8) + n0];
            U4 u;
            u.h = f16x4{ (f16)(acc[nb][4 * p + 0] + b4[0]),
                         (f16)(acc[nb][4 * p + 1] + b4[1]),
                         (f16)(acc[nb][4 * p + 2] + b4[2]),
                         (f16)(acc[nb][4 * p + 3] + b4[3]) };
            H2i[nb * 8 + 2 * p]     = u.i[0];
            H2i[nb * 8 + 2 * p + 1] = u.i[1];
        }
        #pragma unroll
        for (int e = 0; e < 16; ++e) acc[nb][e] = 0.f;
    }

    // ---- GEMM2: acc = H2 @ Wg ; H2^T B-frag via 2-shfl half-partner exchange ----
    // lane needs k = kt*16 + h*8 + j: j0..3 from lane (col) [self if h=0], j4..7 from
    // col+32 [self if h=1]; value = source's reg-quad q = 2*(kt&1)+h_req of nb=kt>>1.
    #pragma unroll
    for (int s = 0; s < 8; ++s) {
        if (s < 7) stage(Wgv, s + 1, (s + 1) & 1);
        #pragma unroll
        for (int t = 0; t < 2; ++t) {
            const int b = s * 8 + 4 * t;   // ints: qlo = {b,b+1}, qhi = {b+2,b+3}
            int S0 = h ? H2i[b]     : H2i[b + 2];   // what partner needs
            int S1 = h ? H2i[b + 1] : H2i[b + 3];
            int T0 = h ? H2i[b + 2] : H2i[b];       // what self needs
            int T1 = h ? H2i[b + 3] : H2i[b + 1];
            int R0 = __shfl(S0, lane ^ 32);
            int R1 = __shfl(S1, lane ^ 32);
            U8 u;
            u.i[0] = h ? R0 : T0;
            u.i[1] = h ? R1 : T1;
            u.i[2] = h ? T0 : R0;
            u.i[3] = h ? T1 : R1;
            const int chunk = ((t << 1) + h) ^ cxor;
            #pragma unroll
            for (int nb = 0; nb < 8; ++nb) {
                f16x8 af = *(const f16x8*)&Wb[s & 1][(nb << 10) + rowoff + (chunk << 3)];
                acc[nb] = __builtin_amdgcn_mfma_f32_32x32x16_f16(af, u.h, acc[nb], 0, 0, 0);
            }
        }
        if (s < 7) __syncthreads();
    }

    // ---- gating + LN stats, all in registers ----
    float sr = 0.f, qr = 0.f;
    #pragma unroll
    for (int nb = 0; nb < 8; ++nb) {
        #pragma unroll
        for (int p = 0; p < 4; ++p) {
            int n0 = (nb << 5) + (p << 3) + (h << 2);
            f32x4 bgv = *(const f32x4*)&bg[(v << 8) + n0];
            U4 u2; u2.i[0] = H2i[nb * 8 + 2 * p]; u2.i[1] = H2i[nb * 8 + 2 * p + 1];
            #pragma unroll
            for (int r = 0; r < 4; ++r) {
                float a = acc[nb][4 * p + r] + bgv[r];
                float g = 1.f / (1.f + __expf(-a));
                float val = g * (float)u2.h[r];
                acc[nb][4 * p + r] = val;
                sr += val; qr += val * val;
            }
        }
    }
    sr += __shfl_xor(sr, 32);
    qr += __shfl_xor(qr, 32);
    float mu  = sr * (1.f / 256.f);
    float var = qr * (1.f / 256.f) - mu * mu;
    float inv = rsqrtf(var + LN_EPS_F);

    // ---- normalize + score + VO write ----
    float sp = 0.f;
    f16* VOr = VO + ((size_t)v * T_TOK + m) * H_N;
    #pragma unroll
    for (int nb = 0; nb < 8; ++nb) {
        #pragma unroll
        for (int p = 0; p < 4; ++p) {
            int n0 = (nb << 5) + (p << 3) + (h << 2);
            f32x4 gm = *(const f32x4*)&gamma[(v << 8) + n0];
            f32x4 bt = *(const f32x4*)&beta[(v << 8) + n0];
            f32x4 wa = *(const f32x4*)&Wa[n0];
            f16x4 ov;
            #pragma unroll
            for (int r = 0; r < 4; ++r) {
                float o = (acc[nb][4 * p + r] - mu) * inv * gm[r] + bt[r];
                sp += o * wa[r];
                ov[r] = (f16)o;
            }
            *(f16x4*)&VOr[n0] = ov;
        }
    }
    sp += __shfl_xor(sp, 32);
    if (h == 0) scores[(size_t)m * V_N + v] = sp + ba[0];
}

// ---------------- softmax over V + pooled sum ----------------
__global__ __launch_bounds__(128) void pool(
    const f16* __restrict__ VO,       // [V][T][H]
    const float* __restrict__ scores, // [T][V]
    float* __restrict__ out)          // [T*H] vsn, then [T*V] attn
{
    int t = blockIdx.x, tid = threadIdx.x;
    __shared__ float sc[V_N];
    if (tid < V_N) sc[tid] = scores[t * V_N + tid];
    __syncthreads();
    float mx = -1e30f;
    #pragma unroll
    for (int v = 0; v < V_N; ++v) mx = fmaxf(mx, sc[v]);
    float e[V_N];
    float sum = 0.f;
    #pragma unroll
    for (int v = 0; v < V_N; ++v) { e[v] = __expf(sc[v] - mx); sum += e[v]; }
    float isum = 1.f / sum;
    float a0 = 0.f, a1 = 0.f;
    #pragma unroll
    for (int v = 0; v < V_N; ++v) {
        f16x2 vv = *(const f16x2*)&VO[((size_t)v * T_TOK + t) * H_N + tid * 2];
        float ww = e[v] * isum;
        a0 = fmaf((float)vv[0], ww, a0);
        a1 = fmaf((float)vv[1], ww, a1);
    }
    *(float2*)&out[(size_t)t * H_N + tid * 2] = make_float2(a0, a1);
    if (tid < V_N)
        out[(size_t)T_TOK * H_N + (size_t)t * V_N + tid] = e[tid] * isum;
}

extern "C" void kernel_launch(void* const* d_in, const int* in_sizes, int n_in,
                              void* d_out, int out_size, void* d_ws, size_t ws_size,
                              hipStream_t stream)
{
    const float* x     = (const float*)d_in[0];
    const float* W1    = (const float*)d_in[1];
    const float* b1    = (const float*)d_in[2];
    const float* W2    = (const float*)d_in[3];
    const float* b2    = (const float*)d_in[4];
    const float* Wg    = (const float*)d_in[5];
    const float* bg    = (const float*)d_in[6];
    const float* gamma = (const float*)d_in[7];
    const float* beta  = (const float*)d_in[8];
    const float* Wa    = (const float*)d_in[9];
    const float* ba    = (const float*)d_in[10];
    float* out = (float*)d_out;

    char* ws = (char*)d_ws;
    f16* W2t = (f16*)ws;                                        // 4 MB
    f16* Wgt = (f16*)(ws + ((size_t)4 << 20));                  // 4 MB
    f16* VO  = (f16*)(ws + ((size_t)8 << 20));                  // 64 MB
    float* scores = (float*)(ws + ((size_t)72 << 20));          // 512 KB
    f16* W1h = (f16*)(ws + ((size_t)72 << 20) + (512 << 10));   // 16 KB
    f16* b1h = (f16*)(ws + ((size_t)72 << 20) + (528 << 10));   // 16 KB

    prep_transpose<<<1024, 256, 0, stream>>>(W2, Wg, W2t, Wgt);
    prep_w1<<<32, 256, 0, stream>>>(W1, b1, W1h, b1h);
    fused_grn<<<1024, 256, 0, stream>>>(x, W1h, b1h, W2t, b2, Wgt, bg,
                                        gamma, beta, Wa, ba, VO, scores);
    pool<<<4096, 128, 0, stream>>>(VO, scores, out);
}

// Round 8
// 111.355 us; speedup vs baseline: 1.2992x; 1.2992x over previous
//
#include <hip/hip_runtime.h>
#include <hip/hip_bf16.h>

typedef _Float16 f16;
typedef _Float16 f16x2 __attribute__((ext_vector_type(2)));
typedef _Float16 f16x4 __attribute__((ext_vector_type(4)));
typedef _Float16 f16x8 __attribute__((ext_vector_type(8)));
typedef float f32x4 __attribute__((ext_vector_type(4)));

#define T_TOK 4096
#define V_N 32
#define H_N 256
#define LN_EPS_F 1e-5f
#define H2PAD 264   // f16 row stride of H2L: 528B -> uniform bank spread

union U4 { f16x4 h; int i[2]; };

__device__ __forceinline__ void gload16(const f16* g, f16* l) {
    __builtin_amdgcn_global_load_lds(
        (const __attribute__((address_space(1))) void*)g,
        (__attribute__((address_space(3))) void*)l, 16, 0, 0);
}

// ---------------- prep: W2,Wg [v][k][n] f32 -> [v][n][k] f16 ----------------
__global__ __launch_bounds__(256) void prep_transpose(
    const float* __restrict__ W2, const float* __restrict__ Wg,
    f16* __restrict__ W2t, f16* __restrict__ Wgt)
{
    __shared__ float tile[64][65];
    int bid = blockIdx.x;
    int w = bid >> 9;
    int rem = bid & 511;
    int v = rem >> 4;
    int kt = (rem >> 2) & 3;
    int nt = rem & 3;
    const float* src = w ? Wg : W2;
    f16* dst = w ? Wgt : W2t;
    const float* base = src + ((size_t)v * H_N + (size_t)kt * 64) * H_N + nt * 64;
    int tid = threadIdx.x;
    #pragma unroll
    for (int p = 0; p < 16; ++p) {
        int idx = p * 256 + tid;
        int r = idx >> 6, c = idx & 63;
        tile[r][c] = base[(size_t)r * H_N + c];
    }
    __syncthreads();
    f16* obase = dst + ((size_t)v * H_N + (size_t)nt * 64) * H_N + kt * 64;
    #pragma unroll
    for (int p = 0; p < 16; ++p) {
        int idx = p * 256 + tid;
        int r = idx >> 6, c = idx & 63;
        obase[(size_t)r * H_N + c] = (f16)tile[c][r];
    }
}

// ---------------- prep: W1,b1 f32 -> f16 ----------------
__global__ __launch_bounds__(256) void prep_w1(
    const float* __restrict__ W1, const float* __restrict__ b1,
    f16* __restrict__ W1h, f16* __restrict__ b1h)
{
    int i = blockIdx.x * 256 + threadIdx.x;   // grid 32 -> 8192
    W1h[i] = (f16)W1[i];
    b1h[i] = (f16)b1[i];
}

// ---------------- fused GRN: swapped-operand, n-split wave pairs, G=2 ----------------
// grid 2048 = (v, mt64), 256 thr = 4 waves (2 pairs). Pair p = w>>1 owns 32 tokens;
// wave handles n-half (w&1). Each af (weight frag) feeds 2 MFMAs (2 token groups).
// GEMM2's H2^T B-operand via padded LDS buffer H2L written at GEMM1 end.
// Swizzle invariant (rule #21): stage stores global chunk (c ^ (n&3)) at slot c;
// reader fetches global chunk hi from slot hi ^ (n&3) = hi ^ (lo&3). BOTH sides match.
__global__ __launch_bounds__(256, 2) void fused_grn(
    const float* __restrict__ x,    // [T][V]
    const f16* __restrict__ W1h, const f16* __restrict__ b1h,   // [V][256]
    const f16* __restrict__ W2t, const float* __restrict__ b2,  // [V][n][k]
    const f16* __restrict__ Wgt, const float* __restrict__ bg,
    const float* __restrict__ gamma, const float* __restrict__ beta,
    const float* __restrict__ Wa, const float* __restrict__ ba,
    f16* __restrict__ VO,           // [V][T][H]
    float* __restrict__ scores)     // [T][V]
{
    __shared__ f16 Wb[2][256 * 32];      // 32 KB: double-buffered weight k-slices
    __shared__ f16 H2L[64 * H2PAD];      // 33 KB: H2 (post-b2) for GEMM2 B-operand
    __shared__ float sqx[4][2][16][2];   // cross-pair LN partials
    __shared__ float spx[4][2][16];      // cross-pair score partials

    int bid = blockIdx.x;
    int xcd = bid & 7, rr = bid >> 3;
    int v  = (xcd << 2) + (rr >> 6);     // 4 variables per XCD -> weights L2-local
    int mt = rr & 63;
    int tid = threadIdx.x;
    int w = tid >> 6, lane = tid & 63;
    int lo = lane & 15, hi = lane >> 4;
    int pair = w >> 1, nhalf = w & 1;
    int tokl0 = pair * 32 + lo;          // block-local token of group 0
    int m0 = mt * 64 + tokl0;            // global token of group 0 (g=1: +16)

    const f16* W2v = W2t + ((size_t)v << 16);
    const f16* Wgv = Wgt + ((size_t)v << 16);

    // stage k-slice s (256n x 32k) into Wb[buf]; linear dest, source chunk-swizzled:
    // slot c of row n receives global chunk c ^ (n&3)  [n&3 = (lane>>2)&3]
    auto stage = [&](const f16* Wv, int s, int buf) {
        int cs = (lane & 3) ^ ((lane >> 2) & 3);
        #pragma unroll
        for (int i = 0; i < 4; ++i) {
            int n = ((w * 4 + i) << 4) + (lane >> 2);
            gload16(Wv + ((size_t)n << 8) + (s << 5) + (cs << 3),
                    &Wb[buf][(w * 4 + i) << 9]);
        }
    };

    float xs0 = x[(size_t)m0 * V_N + v];
    float xs1 = x[(size_t)(m0 + 16) * V_N + v];
    f16 xh0 = (f16)xs0, xh1 = (f16)xs1;
    f16x8 x80 = { xh0, xh0, xh0, xh0, xh0, xh0, xh0, xh0 };
    f16x8 x81 = { xh1, xh1, xh1, xh1, xh1, xh1, xh1, xh1 };

    f32x4 acc0[8] = {}, acc1[8] = {};    // [nf]: n = nhalf*128 + nf*16 + hi*4 + r
    // read slot for global chunk hi of row n (n&15 == lo): hi ^ (lo&3)   [FIX r7->r8]
    const int afbase = ((hi ^ (lo & 3)) << 3);
    const int rbase = (nhalf * 128 + lo) << 5;   // + (nf*16)<<5 per nf

    stage(W2v, 0, 0);
    __syncthreads();

    // ---- GEMM1: H2 = relu(x*W1+b1) @ W2 ; one af feeds both token groups ----
    #pragma unroll
    for (int s = 0; s < 8; ++s) {
        if (s < 7) stage(W2v, s + 1, (s + 1) & 1);
        else       stage(Wgv, 0, 0);            // prefetch GEMM2 slice 0
        const int k0 = (s << 5) + (hi << 3);
        f16x8 w8 = *(const f16x8*)&W1h[(v << 8) + k0];
        f16x8 c8 = *(const f16x8*)&b1h[(v << 8) + k0];
        f16x8 hv0 = x80 * w8 + c8;
        f16x8 hv1 = x81 * w8 + c8;
        #pragma unroll
        for (int j = 0; j < 8; ++j) {
            hv0[j] = hv0[j] > (f16)0 ? hv0[j] : (f16)0;
            hv1[j] = hv1[j] > (f16)0 ? hv1[j] : (f16)0;
        }
        #pragma unroll
        for (int nf = 0; nf < 8; ++nf) {
            f16x8 af = *(const f16x8*)&Wb[s & 1][rbase + (nf << 9) + afbase];
            acc0[nf] = __builtin_amdgcn_mfma_f32_16x16x32_f16(af, hv0, acc0[nf], 0, 0, 0);
            acc1[nf] = __builtin_amdgcn_mfma_f32_16x16x32_f16(af, hv1, acc1[nf], 0, 0, 0);
        }
        __syncthreads();
    }

    // ---- H2 += b2, pack (registers) + write to H2L for the GEMM2 B-operand ----
    int H2p0[8][2], H2p1[8][2];
    #pragma unroll
    for (int nf = 0; nf < 8; ++nf) {
        int n0 = nhalf * 128 + nf * 16 + hi * 4;
        f32x4 b4 = *(const f32x4*)&b2[(v << 8) + n0];
        f32x4 h0 = acc0[nf] + b4;
        f32x4 h1 = acc1[nf] + b4;
        U4 u0; u0.h = f16x4{ (f16)h0[0], (f16)h0[1], (f16)h0[2], (f16)h0[3] };
        U4 u1; u1.h = f16x4{ (f16)h1[0], (f16)h1[1], (f16)h1[2], (f16)h1[3] };
        H2p0[nf][0] = u0.i[0]; H2p0[nf][1] = u0.i[1];
        H2p1[nf][0] = u1.i[0]; H2p1[nf][1] = u1.i[1];
        *(f16x4*)&H2L[tokl0 * H2PAD + n0]        = u0.h;
        *(f16x4*)&H2L[(tokl0 + 16) * H2PAD + n0] = u1.h;
        acc0[nf] = f32x4{0.f, 0.f, 0.f, 0.f};
        acc1[nf] = f32x4{0.f, 0.f, 0.f, 0.f};
    }
    __syncthreads();   // H2L complete + Wg slice 0 staged (vmcnt drained)

    // ---- GEMM2: acc = H2 @ Wg ; B-frag = clean ds_read_b128 from H2L ----
    #pragma unroll
    for (int s = 0; s < 8; ++s) {
        if (s < 7) stage(Wgv, s + 1, (s + 1) & 1);
        const int kof = (s << 5) + (hi << 3);
        f16x8 bf0 = *(const f16x8*)&H2L[tokl0 * H2PAD + kof];
        f16x8 bf1 = *(const f16x8*)&H2L[(tokl0 + 16) * H2PAD + kof];
        #pragma unroll
        for (int nf = 0; nf < 8; ++nf) {
            f16x8 af = *(const f16x8*)&Wb[s & 1][rbase + (nf << 9) + afbase];
            acc0[nf] = __builtin_amdgcn_mfma_f32_16x16x32_f16(af, bf0, acc0[nf], 0, 0, 0);
            acc1[nf] = __builtin_amdgcn_mfma_f32_16x16x32_f16(af, bf1, acc1[nf], 0, 0, 0);
        }
        if (s < 7) __syncthreads();
    }

    // ---- gating (in-register) + LN partials over this wave's n-half ----
    float s0 = 0.f, q0 = 0.f, s1 = 0.f, q1 = 0.f;
    #pragma unroll
    for (int nf = 0; nf < 8; ++nf) {
        int n0 = nhalf * 128 + nf * 16 + hi * 4;
        f32x4 bgv = *(const f32x4*)&bg[(v << 8) + n0];
        U4 u0; u0.i[0] = H2p0[nf][0]; u0.i[1] = H2p0[nf][1];
        U4 u1; u1.i[0] = H2p1[nf][0]; u1.i[1] = H2p1[nf][1];
        #pragma unroll
        for (int r = 0; r < 4; ++r) {
            float a0 = acc0[nf][r] + bgv[r];
            float g0 = 1.f / (1.f + __expf(-a0));
            float v0 = g0 * (float)u0.h[r];
            acc0[nf][r] = v0; s0 += v0; q0 += v0 * v0;
            float a1 = acc1[nf][r] + bgv[r];
            float g1 = 1.f / (1.f + __expf(-a1));
            float v1 = g1 * (float)u1.h[r];
            acc1[nf][r] = v1; s1 += v1; q1 += v1 * v1;
        }
    }
    s0 += __shfl_xor(s0, 16); s0 += __shfl_xor(s0, 32);
    q0 += __shfl_xor(q0, 16); q0 += __shfl_xor(q0, 32);
    s1 += __shfl_xor(s1, 16); s1 += __shfl_xor(s1, 32);
    q1 += __shfl_xor(q1, 16); q1 += __shfl_xor(q1, 32);
    if (hi == 0) {
        sqx[w][0][lo][0] = s0; sqx[w][0][lo][1] = q0;
        sqx[w][1][lo][0] = s1; sqx[w][1][lo][1] = q1;
    }
    __syncthreads();
    float st0 = s0 + sqx[w ^ 1][0][lo][0], qt0 = q0 + sqx[w ^ 1][0][lo][1];
    float st1 = s1 + sqx[w ^ 1][1][lo][0], qt1 = q1 + sqx[w ^ 1][1][lo][1];
    float mu0  = st0 * (1.f / 256.f);
    float var0 = qt0 * (1.f / 256.f) - mu0 * mu0;
    float inv0 = rsqrtf(var0 + LN_EPS_F);
    float mu1  = st1 * (1.f / 256.f);
    float var1 = qt1 * (1.f / 256.f) - mu1 * mu1;
    float inv1 = rsqrtf(var1 + LN_EPS_F);

    // ---- normalize + score partial + VO write (own n-half) ----
    float sp0 = 0.f, sp1 = 0.f;
    f16* VOr0 = VO + ((size_t)v * T_TOK + m0) * H_N;
    f16* VOr1 = VOr0 + 16 * H_N;
    #pragma unroll
    for (int nf = 0; nf < 8; ++nf) {
        int n0 = nhalf * 128 + nf * 16 + hi * 4;
        f32x4 gm = *(const f32x4*)&gamma[(v << 8) + n0];
        f32x4 bt = *(const f32x4*)&beta[(v << 8) + n0];
        f32x4 wa = *(const f32x4*)&Wa[n0];
        f16x4 ov0, ov1;
        #pragma unroll
        for (int r = 0; r < 4; ++r) {
            float o0 = (acc0[nf][r] - mu0) * inv0 * gm[r] + bt[r];
            sp0 += o0 * wa[r];
            ov0[r] = (f16)o0;
            float o1 = (acc1[nf][r] - mu1) * inv1 * gm[r] + bt[r];
            sp1 += o1 * wa[r];
            ov1[r] = (f16)o1;
        }
        *(f16x4*)&VOr0[n0] = ov0;
        *(f16x4*)&VOr1[n0] = ov1;
    }
    sp0 += __shfl_xor(sp0, 16); sp0 += __shfl_xor(sp0, 32);
    sp1 += __shfl_xor(sp1, 16); sp1 += __shfl_xor(sp1, 32);
    if (hi == 0) { spx[w][0][lo] = sp0; spx[w][1][lo] = sp1; }
    __syncthreads();
    if (nhalf == 0 && hi == 0) {
        scores[(size_t)m0 * V_N + v]        = sp0 + spx[w ^ 1][0][lo] + ba[0];
        scores[(size_t)(m0 + 16) * V_N + v] = sp1 + spx[w ^ 1][1][lo] + ba[0];
    }
}

// ---------------- softmax over V + pooled sum ----------------
__global__ __launch_bounds__(128) void pool(
    const f16* __restrict__ VO,       // [V][T][H]
    const float* __restrict__ scores, // [T][V]
    float* __restrict__ out)          // [T*H] vsn, then [T*V] attn
{
    int t = blockIdx.x, tid = threadIdx.x;
    __shared__ float sc[V_N];
    if (tid < V_N) sc[tid] = scores[t * V_N + tid];
    __syncthreads();
    float mx = -1e30f;
    #pragma unroll
    for (int v = 0; v < V_N; ++v) mx = fmaxf(mx, sc[v]);
    float e[V_N];
    float sum = 0.f;
    #pragma unroll
    for (int v = 0; v < V_N; ++v) { e[v] = __expf(sc[v] - mx); sum += e[v]; }
    float isum = 1.f / sum;
    float a0 = 0.f, a1 = 0.f;
    #pragma unroll
    for (int v = 0; v < V_N; ++v) {
        f16x2 vv = *(const f16x2*)&VO[((size_t)v * T_TOK + t) * H_N + tid * 2];
        float ww = e[v] * isum;
        a0 = fmaf((float)vv[0], ww, a0);
        a1 = fmaf((float)vv[1], ww, a1);
    }
    *(float2*)&out[(size_t)t * H_N + tid * 2] = make_float2(a0, a1);
    if (tid < V_N)
        out[(size_t)T_TOK * H_N + (size_t)t * V_N + tid] = e[tid] * isum;
}

extern "C" void kernel_launch(void* const* d_in, const int* in_sizes, int n_in,
                              void* d_out, int out_size, void* d_ws, size_t ws_size,
                              hipStream_t stream)
{
    const float* x     = (const float*)d_in[0];
    const float* W1    = (const float*)d_in[1];
    const float* b1    = (const float*)d_in[2];
    const float* W2    = (const float*)d_in[3];
    const float* b2    = (const float*)d_in[4];
    const float* Wg    = (const float*)d_in[5];
    const float* bg    = (const float*)d_in[6];
    const float* gamma = (const float*)d_in[7];
    const float* beta  = (const float*)d_in[8];
    const float* Wa    = (const float*)d_in[9];
    const float* ba    = (const float*)d_in[10];
    float* out = (float*)d_out;

    char* ws = (char*)d_ws;
    f16* W2t = (f16*)ws;                                        // 4 MB
    f16* Wgt = (f16*)(ws + ((size_t)4 << 20));                  // 4 MB
    f16* VO  = (f16*)(ws + ((size_t)8 << 20));                  // 64 MB
    float* scores = (float*)(ws + ((size_t)72 << 20));          // 512 KB
    f16* W1h = (f16*)(ws + ((size_t)72 << 20) + (512 << 10));   // 16 KB
    f16* b1h = (f16*)(ws + ((size_t)72 << 20) + (528 << 10));   // 16 KB

    prep_transpose<<<1024, 256, 0, stream>>>(W2, Wg, W2t, Wgt);
    prep_w1<<<32, 256, 0, stream>>>(W1, b1, W1h, b1h);
    fused_grn<<<2048, 256, 0, stream>>>(x, W1h, b1h, W2t, b2, Wgt, bg,
                                        gamma, beta, Wa, ba, VO, scores);
    pool<<<4096, 128, 0, stream>>>(VO, scores, out);
}

// Round 9
// 104.750 us; speedup vs baseline: 1.3811x; 1.0631x over previous
//
#include <hip/hip_runtime.h>
#include <hip/hip_bf16.h>

typedef _Float16 f16;
typedef _Float16 f16x2 __attribute__((ext_vector_type(2)));
typedef _Float16 f16x4 __attribute__((ext_vector_type(4)));
typedef _Float16 f16x8 __attribute__((ext_vector_type(8)));
typedef float f32x4 __attribute__((ext_vector_type(4)));

#define T_TOK 4096
#define V_N 32
#define H_N 256
#define LN_EPS_F 1e-5f

union U4 { f16x4 h; int i[2]; };

__device__ __forceinline__ void gload16(const f16* g, f16* l) {
    __builtin_amdgcn_global_load_lds(
        (const __attribute__((address_space(1))) void*)g,
        (__attribute__((address_space(3))) void*)l, 16, 0, 0);
}

// counted-vmcnt barrier: keep the newest stage (4 loads) in flight across it
#define WAITB4 { asm volatile("s_waitcnt vmcnt(4) lgkmcnt(0)" ::: "memory"); \
                 __builtin_amdgcn_s_barrier(); }
#define WAITB0 { asm volatile("s_waitcnt vmcnt(0) lgkmcnt(0)" ::: "memory"); \
                 __builtin_amdgcn_s_barrier(); }

// ---------------- prep: W2,Wg [v][k][n] f32 -> [v][n][k] f16 ----------------
__global__ __launch_bounds__(256) void prep_transpose(
    const float* __restrict__ W2, const float* __restrict__ Wg,
    f16* __restrict__ W2t, f16* __restrict__ Wgt)
{
    __shared__ float tile[64][65];
    int bid = blockIdx.x;
    int w = bid >> 9;
    int rem = bid & 511;
    int v = rem >> 4;
    int kt = (rem >> 2) & 3;
    int nt = rem & 3;
    const float* src = w ? Wg : W2;
    f16* dst = w ? Wgt : W2t;
    const float* base = src + ((size_t)v * H_N + (size_t)kt * 64) * H_N + nt * 64;
    int tid = threadIdx.x;
    #pragma unroll
    for (int p = 0; p < 16; ++p) {
        int idx = p * 256 + tid;
        int r = idx >> 6, c = idx & 63;
        tile[r][c] = base[(size_t)r * H_N + c];
    }
    __syncthreads();
    f16* obase = dst + ((size_t)v * H_N + (size_t)nt * 64) * H_N + kt * 64;
    #pragma unroll
    for (int p = 0; p < 16; ++p) {
        int idx = p * 256 + tid;
        int r = idx >> 6, c = idx & 63;
        obase[(size_t)r * H_N + c] = (f16)tile[c][r];
    }
}

// ---------------- prep: W1,b1 f32 -> f16 ----------------
__global__ __launch_bounds__(256) void prep_w1(
    const float* __restrict__ W1, const float* __restrict__ b1,
    f16* __restrict__ W1h, f16* __restrict__ b1h)
{
    int i = blockIdx.x * 256 + threadIdx.x;   // grid 32 -> 8192
    W1h[i] = (f16)W1[i];
    b1h[i] = (f16)b1[i];
}

// ---------------- fused GRN: n-split wave pairs, triple-buffer counted-vmcnt ----
// grid 2048 = (v, mt64), 256 thr = 4 waves (2 pairs). Pair owns 32 tokens; wave
// handles n-half. 16 weight k-slices (slice g: g<8 = W2[g], else Wg[g-8]) staged
// into 3 LDS buffers (buf = g%3), prefetch distance 2, vmcnt(4) barriers.
// h1 fully precomputed in registers (no in-loop global loads).
__global__ __launch_bounds__(256, 2) void fused_grn(
    const float* __restrict__ x,    // [T][V]
    const f16* __restrict__ W1h, const f16* __restrict__ b1h,   // [V][256]
    const f16* __restrict__ W2t, const float* __restrict__ b2,  // [V][n][k]
    const f16* __restrict__ Wgt, const float* __restrict__ bg,
    const float* __restrict__ gamma, const float* __restrict__ beta,
    const float* __restrict__ Wa, const float* __restrict__ ba,
    f16* __restrict__ VO,           // [V][T][H]
    float* __restrict__ scores)     // [T][V]
{
    __shared__ __align__(16) char ldsraw[81920];
    f16* Wb  = (f16*)ldsraw;               // 3 x 8192 f16 (48 KB)
    f16* H2L = (f16*)(ldsraw + 49152);     // 64 x 256 f16, granule-XOR swizzled (32 KB)
    // overlay on Wb buf1 (dead after GEMM2 s=5):
    float* sqx = (float*)(ldsraw + 16384); // [w][g][lo][2]  (4*2*16*2 floats)
    float* spx = (float*)(ldsraw + 17408); // [w][g][lo]

    int bid = blockIdx.x;
    int xcd = bid & 7, rr = bid >> 3;
    int v  = (xcd << 2) + (rr >> 6);       // 4 variables per XCD -> weights L2-local
    int mt = rr & 63;
    int tid = threadIdx.x;
    int w = tid >> 6, lane = tid & 63;
    int lo = lane & 15, hi = lane >> 4;
    int pair = w >> 1, nhalf = w & 1;
    int tokl0 = pair * 32 + lo;            // block-local token of group 0 (g1: +16)
    int m0 = mt * 64 + tokl0;

    const f16* W2v = W2t + ((size_t)v << 16);
    const f16* Wgv = Wgt + ((size_t)v << 16);

    // stage slice g into Wb[g%3]; linear dest, source chunk-swizzled:
    // slot c of row n holds global chunk c ^ (n&3)   [verified r8]
    auto stageg = [&](int g) {
        const f16* Wv = (g < 8) ? W2v : Wgv;
        int s = (g < 8) ? g : g - 8;
        int buf = g % 3;
        int cs = (lane & 3) ^ ((lane >> 2) & 3);
        #pragma unroll
        for (int i = 0; i < 4; ++i) {
            int n = ((w * 4 + i) << 4) + (lane >> 2);
            gload16(Wv + ((size_t)n << 8) + (s << 5) + (cs << 3),
                    &Wb[buf * 8192 + ((w * 4 + i) << 9)]);
        }
    };

    stageg(0);
    stageg(1);

    // ---- precompute h1 = relu(x*W1+b1) for both token groups, all 8 slices ----
    float xs0 = x[(size_t)m0 * V_N + v];
    float xs1 = x[(size_t)(m0 + 16) * V_N + v];
    f16 xh0 = (f16)xs0, xh1 = (f16)xs1;
    f16x8 x80 = { xh0, xh0, xh0, xh0, xh0, xh0, xh0, xh0 };
    f16x8 x81 = { xh1, xh1, xh1, xh1, xh1, xh1, xh1, xh1 };
    f16x8 hv0[8], hv1[8];
    #pragma unroll
    for (int s = 0; s < 8; ++s) {
        const int k0 = (s << 5) + (hi << 3);
        f16x8 w8 = *(const f16x8*)&W1h[(v << 8) + k0];
        f16x8 c8 = *(const f16x8*)&b1h[(v << 8) + k0];
        f16x8 a = x80 * w8 + c8;
        f16x8 b = x81 * w8 + c8;
        #pragma unroll
        for (int j = 0; j < 8; ++j) {
            a[j] = a[j] > (f16)0 ? a[j] : (f16)0;
            b[j] = b[j] > (f16)0 ? b[j] : (f16)0;
        }
        hv0[s] = a; hv1[s] = b;
    }

    f32x4 acc0[8] = {}, acc1[8] = {};      // [nf]: n = nhalf*128 + nf*16 + hi*4 + r
    const int afbase = ((hi ^ (lo & 3)) << 3);
    const int rbase = (nhalf * 128 + lo) << 5;

    WAITB4   // slice 0 complete; slice 1 (4 loads) stays in flight

    // ---- GEMM1: 8 steps; stage slice s+2; vmcnt(4) barrier ----
    #pragma unroll
    for (int s = 0; s < 8; ++s) {
        stageg(s + 2);
        const f16* B = &Wb[(s % 3) * 8192];
        #pragma unroll
        for (int nf = 0; nf < 8; ++nf) {
            f16x8 af = *(const f16x8*)&B[rbase + (nf << 9) + afbase];
            acc0[nf] = __builtin_amdgcn_mfma_f32_16x16x32_f16(af, hv0[s], acc0[nf], 0, 0, 0);
            acc1[nf] = __builtin_amdgcn_mfma_f32_16x16x32_f16(af, hv1[s], acc1[nf], 0, 0, 0);
        }
        WAITB4
    }

    // ---- H2 += b2, pack (registers) + swizzled H2L write ----
    int H2p0[8][2], H2p1[8][2];
    #pragma unroll
    for (int nf = 0; nf < 8; ++nf) {
        int n0 = nhalf * 128 + nf * 16 + hi * 4;
        f32x4 b4 = *(const f32x4*)&b2[(v << 8) + n0];
        f32x4 h0 = acc0[nf] + b4;
        f32x4 h1 = acc1[nf] + b4;
        U4 u0; u0.h = f16x4{ (f16)h0[0], (f16)h0[1], (f16)h0[2], (f16)h0[3] };
        U4 u1; u1.h = f16x4{ (f16)h1[0], (f16)h1[1], (f16)h1[2], (f16)h1[3] };
        H2p0[nf][0] = u0.i[0]; H2p0[nf][1] = u0.i[1];
        H2p1[nf][0] = u1.i[0]; H2p1[nf][1] = u1.i[1];
        int gw = nhalf * 16 + nf * 2 + (hi >> 1);
        int woff = ((gw ^ (lo & 7)) << 3) + ((hi & 1) << 2);
        *(f16x4*)&H2L[tokl0 * 256 + woff]        = u0.h;
        *(f16x4*)&H2L[(tokl0 + 16) * 256 + woff] = u1.h;
        acc0[nf] = f32x4{0.f, 0.f, 0.f, 0.f};
        acc1[nf] = f32x4{0.f, 0.f, 0.f, 0.f};
    }
    // H2L visible to the pair; keep slice-9 stage in flight (no vmcnt wait)
    asm volatile("s_waitcnt lgkmcnt(0)" ::: "memory");
    __builtin_amdgcn_s_barrier();

    // ---- GEMM2: 8 steps; B-frag from swizzled H2L; stage Wg slices s+2 ----
    #pragma unroll
    for (int s = 0; s < 8; ++s) {
        if (s < 6) stageg(s + 10);
        const f16* B = &Wb[((s + 8) % 3) * 8192];
        const int grd = (((s << 2) + hi) ^ (lo & 7)) << 3;
        f16x8 bf0 = *(const f16x8*)&H2L[tokl0 * 256 + grd];
        f16x8 bf1 = *(const f16x8*)&H2L[(tokl0 + 16) * 256 + grd];
        #pragma unroll
        for (int nf = 0; nf < 8; ++nf) {
            f16x8 af = *(const f16x8*)&B[rbase + (nf << 9) + afbase];
            acc0[nf] = __builtin_amdgcn_mfma_f32_16x16x32_f16(af, bf0, acc0[nf], 0, 0, 0);
            acc1[nf] = __builtin_amdgcn_mfma_f32_16x16x32_f16(af, bf1, acc1[nf], 0, 0, 0);
        }
        if (s < 6)      WAITB4
        else if (s == 6) WAITB0   // drain: slice 15 complete for s=7; nothing after
    }

    // ---- gating (in-register) + LN partials over this wave's n-half ----
    float s0 = 0.f, q0 = 0.f, s1 = 0.f, q1 = 0.f;
    #pragma unroll
    for (int nf = 0; nf < 8; ++nf) {
        int n0 = nhalf * 128 + nf * 16 + hi * 4;
        f32x4 bgv = *(const f32x4*)&bg[(v << 8) + n0];
        U4 u0; u0.i[0] = H2p0[nf][0]; u0.i[1] = H2p0[nf][1];
        U4 u1; u1.i[0] = H2p1[nf][0]; u1.i[1] = H2p1[nf][1];
        #pragma unroll
        for (int r = 0; r < 4; ++r) {
            float a0 = acc0[nf][r] + bgv[r];
            float g0 = 1.f / (1.f + __expf(-a0));
            float v0 = g0 * (float)u0.h[r];
            acc0[nf][r] = v0; s0 += v0; q0 += v0 * v0;
            float a1 = acc1[nf][r] + bgv[r];
            float g1 = 1.f / (1.f + __expf(-a1));
            float v1 = g1 * (float)u1.h[r];
            acc1[nf][r] = v1; s1 += v1; q1 += v1 * v1;
        }
    }
    s0 += __shfl_xor(s0, 16); s0 += __shfl_xor(s0, 32);
    q0 += __shfl_xor(q0, 16); q0 += __shfl_xor(q0, 32);
    s1 += __shfl_xor(s1, 16); s1 += __shfl_xor(s1, 32);
    q1 += __shfl_xor(q1, 16); q1 += __shfl_xor(q1, 32);
    if (hi == 0) {
        sqx[((w * 2 + 0) * 16 + lo) * 2 + 0] = s0;
        sqx[((w * 2 + 0) * 16 + lo) * 2 + 1] = q0;
        sqx[((w * 2 + 1) * 16 + lo) * 2 + 0] = s1;
        sqx[((w * 2 + 1) * 16 + lo) * 2 + 1] = q1;
    }
    __syncthreads();
    int pw = w ^ 1;
    float st0 = s0 + sqx[((pw * 2 + 0) * 16 + lo) * 2 + 0];
    float qt0 = q0 + sqx[((pw * 2 + 0) * 16 + lo) * 2 + 1];
    float st1 = s1 + sqx[((pw * 2 + 1) * 16 + lo) * 2 + 0];
    float qt1 = q1 + sqx[((pw * 2 + 1) * 16 + lo) * 2 + 1];
    float mu0  = st0 * (1.f / 256.f);
    float var0 = qt0 * (1.f / 256.f) - mu0 * mu0;
    float inv0 = rsqrtf(var0 + LN_EPS_F);
    float mu1  = st1 * (1.f / 256.f);
    float var1 = qt1 * (1.f / 256.f) - mu1 * mu1;
    float inv1 = rsqrtf(var1 + LN_EPS_F);

    // ---- normalize + score partial + VO write (own n-half) ----
    float sp0 = 0.f, sp1 = 0.f;
    f16* VOr0 = VO + ((size_t)v * T_TOK + m0) * H_N;
    f16* VOr1 = VOr0 + 16 * H_N;
    #pragma unroll
    for (int nf = 0; nf < 8; ++nf) {
        int n0 = nhalf * 128 + nf * 16 + hi * 4;
        f32x4 gm = *(const f32x4*)&gamma[(v << 8) + n0];
        f32x4 bt = *(const f32x4*)&beta[(v << 8) + n0];
        f32x4 wa = *(const f32x4*)&Wa[n0];
        f16x4 ov0, ov1;
        #pragma unroll
        for (int r = 0; r < 4; ++r) {
            float o0 = (acc0[nf][r] - mu0) * inv0 * gm[r] + bt[r];
            sp0 += o0 * wa[r];
            ov0[r] = (f16)o0;
            float o1 = (acc1[nf][r] - mu1) * inv1 * gm[r] + bt[r];
            sp1 += o1 * wa[r];
            ov1[r] = (f16)o1;
        }
        *(f16x4*)&VOr0[n0] = ov0;
        *(f16x4*)&VOr1[n0] = ov1;
    }
    sp0 += __shfl_xor(sp0, 16); sp0 += __shfl_xor(sp0, 32);
    sp1 += __shfl_xor(sp1, 16); sp1 += __shfl_xor(sp1, 32);
    if (hi == 0) {
        spx[(w * 2 + 0) * 16 + lo] = sp0;
        spx[(w * 2 + 1) * 16 + lo] = sp1;
    }
    __syncthreads();
    if (nhalf == 0 && hi == 0) {
        scores[(size_t)m0 * V_N + v]        = sp0 + spx[(pw * 2 + 0) * 16 + lo] + ba[0];
        scores[(size_t)(m0 + 16) * V_N + v] = sp1 + spx[(pw * 2 + 1) * 16 + lo] + ba[0];
    }
}

// ---------------- softmax over V + pooled sum ----------------
__global__ __launch_bounds__(128) void pool(
    const f16* __restrict__ VO,       // [V][T][H]
    const float* __restrict__ scores, // [T][V]
    float* __restrict__ out)          // [T*H] vsn, then [T*V] attn
{
    int t = blockIdx.x, tid = threadIdx.x;
    __shared__ float sc[V_N];
    if (tid < V_N) sc[tid] = scores[t * V_N + tid];
    __syncthreads();
    float mx = -1e30f;
    #pragma unroll
    for (int v = 0; v < V_N; ++v) mx = fmaxf(mx, sc[v]);
    float e[V_N];
    float sum = 0.f;
    #pragma unroll
    for (int v = 0; v < V_N; ++v) { e[v] = __expf(sc[v] - mx); sum += e[v]; }
    float isum = 1.f / sum;
    float a0 = 0.f, a1 = 0.f;
    #pragma unroll
    for (int v = 0; v < V_N; ++v) {
        f16x2 vv = *(const f16x2*)&VO[((size_t)v * T_TOK + t) * H_N + tid * 2];
        float ww = e[v] * isum;
        a0 = fmaf((float)vv[0], ww, a0);
        a1 = fmaf((float)vv[1], ww, a1);
    }
    *(float2*)&out[(size_t)t * H_N + tid * 2] = make_float2(a0, a1);
    if (tid < V_N)
        out[(size_t)T_TOK * H_N + (size_t)t * V_N + tid] = e[tid] * isum;
}

extern "C" void kernel_launch(void* const* d_in, const int* in_sizes, int n_in,
                              void* d_out, int out_size, void* d_ws, size_t ws_size,
                              hipStream_t stream)
{
    const float* x     = (const float*)d_in[0];
    const float* W1    = (const float*)d_in[1];
    const float* b1    = (const float*)d_in[2];
    const float* W2    = (const float*)d_in[3];
    const float* b2    = (const float*)d_in[4];
    const float* Wg    = (const float*)d_in[5];
    const float* bg    = (const float*)d_in[6];
    const float* gamma = (const float*)d_in[7];
    const float* beta  = (const float*)d_in[8];
    const float* Wa    = (const float*)d_in[9];
    const float* ba    = (const float*)d_in[10];
    float* out = (float*)d_out;

    char* ws = (char*)d_ws;
    f16* W2t = (f16*)ws;                                        // 4 MB
    f16* Wgt = (f16*)(ws + ((size_t)4 << 20));                  // 4 MB
    f16* VO  = (f16*)(ws + ((size_t)8 << 20));                  // 64 MB
    float* scores = (float*)(ws + ((size_t)72 << 20));          // 512 KB
    f16* W1h = (f16*)(ws + ((size_t)72 << 20) + (512 << 10));   // 16 KB
    f16* b1h = (f16*)(ws + ((size_t)72 << 20) + (528 << 10));   // 16 KB

    prep_transpose<<<1024, 256, 0, stream>>>(W2, Wg, W2t, Wgt);
    prep_w1<<<32, 256, 0, stream>>>(W1, b1, W1h, b1h);
    fused_grn<<<2048, 256, 0, stream>>>(x, W1h, b1h, W2t, b2, Wgt, bg,
                                        gamma, beta, Wa, ba, VO, scores);
    pool<<<4096, 128, 0, stream>>>(VO, scores, out);
}